// Round 1
// baseline (161.712 us; speedup 1.0000x reference)
//
#include <hip/hip_runtime.h>

#define DD 32
#define NSTEP 391
#define NB 128
#define NSITES 784

// Broadcast the value held by lane (group_base + l) to all lanes of each
// 32-lane half. ds_swizzle BitMode: src = ((lane & and) | or_) ^ xor_,
// offset = xor<<10 | or<<5 | and.  and=0, or=l  -> src lane = l.
#define SWZ(ci, l) __int_as_float(__builtin_amdgcn_ds_swizzle((ci), ((l) << 5)))

// 32-term dot: acc round-robin over 4 accumulators to shorten dep chain.
#define SWL(l, acc) acc = fmaf(SWZ(ci, l), av[l], acc);
#define DOT32                                                        \
    SWL(0, s0)  SWL(1, s1)  SWL(2, s2)  SWL(3, s3)                   \
    SWL(4, s0)  SWL(5, s1)  SWL(6, s2)  SWL(7, s3)                   \
    SWL(8, s0)  SWL(9, s1)  SWL(10, s2) SWL(11, s3)                  \
    SWL(12, s0) SWL(13, s1) SWL(14, s2) SWL(15, s3)                  \
    SWL(16, s0) SWL(17, s1) SWL(18, s2) SWL(19, s3)                  \
    SWL(20, s0) SWL(21, s1) SWL(22, s2) SWL(23, s3)                  \
    SWL(24, s0) SWL(25, s1) SWL(26, s2) SWL(27, s3)                  \
    SWL(28, s0) SWL(29, s1) SWL(30, s2) SWL(31, s3)

__global__ __launch_bounds__(64) void mps_chains(
    const float* __restrict__ x,       // (B, 784, 2)
    const float* __restrict__ a0,      // (32, 2)
    const float* __restrict__ coresL,  // (391, 32, 2, 32)
    const float* __restrict__ coresR,  // (391, 32, 2, 32)
    const float* __restrict__ aend,    // (32, 2)
    float* __restrict__ wsL,           // (B, 32)
    float* __restrict__ wsR)           // (B, 32)
{
    __shared__ float2 xsh[392];
    const int tid  = threadIdx.x;
    const int bid  = blockIdx.x;
    const int b    = bid >> 1;
    const int side = bid & 1;
    const int h    = tid >> 5;   // which p-component this half-wave handles
    const int r    = tid & 31;   // output index (r for left, l for right)

    const float2* xb = (const float2*)x + b * NSITES;

    if (side == 0) {
        // ---- left chain: c_new[r] = sum_l c[l] * (x0*A[l,0,r] + x1*A[l,1,r])
        for (int i = tid; i < 392; i += 64) xsh[i] = xb[i];
        __syncthreads();

        float2 xs0 = xsh[0];
        float cv = fmaf(a0[r * 2], xs0.x, a0[r * 2 + 1] * xs0.y);  // v0[r]

        // lane (h,r) reads A[n, l, h, r]: stride 64 floats over l
        const float* p = coresL + h * 32 + r;
        for (int n = 0; n < NSTEP; ++n) {
            float av[32];
            #pragma unroll
            for (int l = 0; l < 32; ++l) av[l] = p[l * 64];
            float2 xs = xsh[n + 1];
            int ci = __float_as_int(cv);
            float s0 = 0.f, s1 = 0.f, s2 = 0.f, s3 = 0.f;
            DOT32
            float dot = (s0 + s1) + (s2 + s3);
            float val = (h ? xs.y : xs.x) * dot;
            val += __shfl_xor(val, 32);   // combine the two p-halves
            cv = val;
            p += 2048;
        }
        if (tid < 32) wsL[b * DD + r] = cv;
    } else {
        // ---- right chain (reverse): c_new[l] = sum_r (x0*A[l,0,r]+x1*A[l,1,r]) * c[r]
        for (int i = tid; i < 392; i += 64) xsh[i] = xb[392 + i];  // x[b, 392..783]
        __syncthreads();

        float2 xe = xsh[391];  // x[b, 783]
        float cv = fmaf(aend[r * 2], xe.x, aend[r * 2 + 1] * xe.y);  // r0[l]

        // lane (h,l) reads A[n, l, h, 0..31]: contiguous 32 floats
        const float* p = coresR + 390 * 2048 + r * 64 + h * 32;
        for (int n = 390; n >= 0; --n) {
            float av[32];
            #pragma unroll
            for (int i4 = 0; i4 < 8; ++i4) {
                float4 v = *(const float4*)(p + i4 * 4);
                av[i4 * 4 + 0] = v.x; av[i4 * 4 + 1] = v.y;
                av[i4 * 4 + 2] = v.z; av[i4 * 4 + 3] = v.w;
            }
            float2 xs = xsh[n];  // x[b, 392 + n]
            int ci = __float_as_int(cv);
            float s0 = 0.f, s1 = 0.f, s2 = 0.f, s3 = 0.f;
            DOT32
            float dot = (s0 + s1) + (s2 + s3);
            float val = (h ? xs.y : xs.x) * dot;
            val += __shfl_xor(val, 32);
            cv = val;
            p -= 2048;
        }
        if (tid < 32) wsR[b * DD + r] = cv;
    }
}

__global__ __launch_bounds__(64) void mps_final(
    const float* __restrict__ wsL, const float* __restrict__ wsR,
    const float* __restrict__ mid,  // core_mid (32, 10, 32)
    float* __restrict__ out)        // (B, 10)
{
    const int b = blockIdx.x;
    const int a = threadIdx.x & 31;
    float pa = wsL[b * 32 + a] * wsR[b * 32 + a];
    #pragma unroll
    for (int c = 0; c < 10; ++c) {
        // mid_diag[a, c] = core_mid[a, c, a]
        float s = pa * mid[a * 320 + c * 32 + a];
        s += __shfl_xor(s, 16, 32);
        s += __shfl_xor(s, 8, 32);
        s += __shfl_xor(s, 4, 32);
        s += __shfl_xor(s, 2, 32);
        s += __shfl_xor(s, 1, 32);
        if (threadIdx.x == 0) out[b * 10 + c] = s;
    }
}

extern "C" void kernel_launch(void* const* d_in, const int* in_sizes, int n_in,
                              void* d_out, int out_size, void* d_ws, size_t ws_size,
                              hipStream_t stream) {
    const float* x      = (const float*)d_in[0];
    const float* a0     = (const float*)d_in[1];
    const float* coresL = (const float*)d_in[2];
    const float* mid    = (const float*)d_in[3];
    const float* coresR = (const float*)d_in[4];
    const float* aend   = (const float*)d_in[5];

    float* wsL = (float*)d_ws;            // 128*32 floats
    float* wsR = wsL + NB * DD;           // 128*32 floats
    float* out = (float*)d_out;

    mps_chains<<<dim3(2 * NB), dim3(64), 0, stream>>>(x, a0, coresL, coresR, aend, wsL, wsR);
    mps_final<<<dim3(NB), dim3(64), 0, stream>>>(wsL, wsR, mid, out);
}